// Round 8
// baseline (98.927 us; speedup 1.0000x reference)
//
#include <hip/hip_runtime.h>

// SEIR SDE: B=32768 x 1000 steps -> out[step][4][B] f32 = 524 MB (write-bound).
// R7 (producer/consumer waves, 97.2us = 233 cyc/step) left a 50 cyc/step gap
// to the ~183 cyc/step HBM-drain floor: __syncthreads() = s_waitcnt vmcnt(0)
// + s_barrier, so each of the 50 chunk boundaries drains the store queue and
// exposes ~1000 cyc of store round-trip tail.
// R8: raw s_barrier with ONLY lgkmcnt(0) (LDS hazard is the real dependency;
// store wave's ds_reads are complete by construction). Global stores stay in
// flight ACROSS barriers (T3/T4 counted-vmcnt mechanism, mirrored to stores);
// register rotation provides the natural throttle; single drain at s_endpgm.

constexpr int   B_TRAJ  = 32768;
constexpr int   NSTEPS  = 1000;
constexpr int   K       = 20;            // steps per chunk
constexpr int   NC      = NSTEPS / K;    // 50 chunks
constexpr float DT      = 0.01f;
constexpr float EPS     = 1e-6f;
constexpr float INV_N   = 1.0f / 10000.0f;   // replaces fdiv (<=1 ulp; thr ~2%)

// Barrier that does NOT drain vmcnt: wave-local LDS ordering only.
// "memory" clobber = compiler fence (no LDS op may cross at IR level);
// lgkmcnt(0) = LDS writes visible before barrier; stores stay outstanding.
__device__ __forceinline__ void barrier_lds_only() {
    asm volatile("s_waitcnt lgkmcnt(0)" ::: "memory");
    __builtin_amdgcn_s_barrier();
    asm volatile("" ::: "memory");
}

__global__ __launch_bounds__(128) void seir_sde_kernel(
    const float* __restrict__ beta,
    const float* __restrict__ sigma,
    const float* __restrict__ gamma,
    const float* __restrict__ S0,
    const float* __restrict__ E0,
    const float* __restrict__ I0,
    const float* __restrict__ R0,
    const float4* __restrict__ dW,   // [NSTEPS] x (w0,w1,w2,w3)
    float* __restrict__ out)         // [NSTEPS][4][B_TRAJ]
{
    __shared__ float4 wbuf[NSTEPS];          // pre-scaled noise, 16 KB
    __shared__ float  ring[2][K][4][64];     // double-buffered chunk, 40 KB

    const float sdt = 0.1f;                  // sqrt(0.01), exact
    for (int i = threadIdx.x; i < NSTEPS; i += 128) {
        const float4 w = dW[i];
        wbuf[i] = make_float4(w.x * sdt, w.y * sdt, w.z * sdt, 0.0f);
    }

    const int lane = threadIdx.x & 63;
    const int wid  = threadIdx.x >> 6;       // 0 = compute wave, 1 = store wave

    // Compute-wave state (dead registers in the store wave).
    float S = 0.f, E = 0.f, I = 0.f, R = 0.f, btn = 0.f, sg = 0.f, gm = 0.f;
    if (wid == 0) {
        const int b = blockIdx.x * 64 + lane;
        S = S0[b]; E = E0[b]; I = I0[b]; R = R0[b];
        btn = beta[0] * INV_N; sg = sigma[0]; gm = gamma[0];
    }

    // Store-wave addressing: lane l -> component (l>>4), trajectories
    // 4*(l&15)..+3 of this block. One dwordx4 = 4 x 256B segments.
    float* const obase = out + blockIdx.x * 64
                             + (lane >> 4) * B_TRAJ + (lane & 15) * 4;

    __syncthreads();                         // noise staged (once; full drain ok)

    // ---- prologue: compute wave fills chunk 0 into ring[0] ----
    if (wid == 0) {
        #pragma unroll 5
        for (int k = 0; k < K; ++k) {
            const float4 w = wbuf[k];
            S = fmaxf(S, EPS); E = fmaxf(E, EPS);
            I = fmaxf(I, EPS); R = fmaxf(R, EPS);
            const float inf = btn * S * I;
            const float ex  = sg * E;
            const float rc  = gm * I;
            const float ni = __builtin_amdgcn_sqrtf(inf);
            const float ne = __builtin_amdgcn_sqrtf(ex);
            const float nr = __builtin_amdgcn_sqrtf(rc);
            const float ai = ni * w.x, ae = ne * w.y, ar = nr * w.z;
            const float Sn = S - inf * DT             - ai;
            const float En = E + (inf - ex) * DT + ai - ae;
            const float In = I + (ex - rc) * DT  + ae - ar;
            const float Rn = R + rc * DT              + ar;
            ring[0][k][0][lane] = Sn;
            ring[0][k][1][lane] = En;
            ring[0][k][2][lane] = In;
            ring[0][k][3][lane] = Rn;
            S = Sn; E = En; I = In; R = Rn;
        }
    }
    barrier_lds_only();

    // ---- pipeline: iter c drains chunk c while filling chunk c+1 ----
    for (int c = 0; c < NC; ++c) {
        if (wid == 0) {
            if (c + 1 < NC) {
                const int s0 = (c + 1) * K;
                float (*rw)[4][64] = ring[(c + 1) & 1];
                #pragma unroll 5
                for (int k = 0; k < K; ++k) {
                    const float4 w = wbuf[s0 + k];
                    S = fmaxf(S, EPS); E = fmaxf(E, EPS);
                    I = fmaxf(I, EPS); R = fmaxf(R, EPS);
                    const float inf = btn * S * I;
                    const float ex  = sg * E;
                    const float rc  = gm * I;
                    const float ni = __builtin_amdgcn_sqrtf(inf);
                    const float ne = __builtin_amdgcn_sqrtf(ex);
                    const float nr = __builtin_amdgcn_sqrtf(rc);
                    const float ai = ni * w.x, ae = ne * w.y, ar = nr * w.z;
                    const float Sn = S - inf * DT             - ai;
                    const float En = E + (inf - ex) * DT + ai - ae;
                    const float In = I + (ex - rc) * DT  + ae - ar;
                    const float Rn = R + rc * DT              + ar;
                    rw[k][0][lane] = Sn;
                    rw[k][1][lane] = En;
                    rw[k][2][lane] = In;
                    rw[k][3][lane] = Rn;
                    S = Sn; E = En; I = In; R = Rn;
                }
            }
        } else {
            // Drain chunk c: K x { 1 ds_read_b128 + 1 global_store_dwordx4 }.
            // Stores are NOT drained at the barrier; they pipeline across
            // chunks, throttled only by register-reuse counted vmcnt.
            const float4* rd = (const float4*)&ring[c & 1][0][0][0];
            float* o = obase + (size_t)(c * K) * (4 * B_TRAJ);
            #pragma unroll
            for (int k = 0; k < K; ++k) {
                const float4 v = rd[k * 64 + lane];   // contiguous 1KB/step
                *(float4*)o = v;
                o += 4 * B_TRAJ;
            }
        }
        barrier_lds_only();
    }
}

extern "C" void kernel_launch(void* const* d_in, const int* in_sizes, int n_in,
                              void* d_out, int out_size, void* d_ws, size_t ws_size,
                              hipStream_t stream) {
    const float*  beta  = (const float*)d_in[0];
    const float*  sigma = (const float*)d_in[1];
    const float*  gamma = (const float*)d_in[2];
    const float*  S0    = (const float*)d_in[3];
    const float*  E0    = (const float*)d_in[4];
    const float*  I0    = (const float*)d_in[5];
    const float*  R0    = (const float*)d_in[6];
    const float4* dW    = (const float4*)d_in[7];
    float* out = (float*)d_out;

    seir_sde_kernel<<<B_TRAJ / 64, 128, 0, stream>>>(
        beta, sigma, gamma, S0, E0, I0, R0, dW, out);
}